// Round 1
// baseline (214.879 us; speedup 1.0000x reference)
//
#include <hip/hip_runtime.h>
#include <math.h>

#ifndef M_PI
#define M_PI 3.14159265358979323846
#endif

#define NSAMP 32768
#define MHALF 16384

__device__ __forceinline__ double dsig(double x) { return 1.0 / (1.0 + exp(-x)); }

// ---------------------------------------------------------------------------
// Kernel 1: per-batch parameter decode (fp64 to match the np/f64 reference)
// computes: rev[b][h] (phase increment in revolutions, double),
//           env[b][h][t] (scan output, 128 frames), amp[b][t], fenv[b][j]
// ---------------------------------------------------------------------------
__global__ __launch_bounds__(128) void prep_kernel(
    const float* __restrict__ packed, const float* __restrict__ freqs,
    double* __restrict__ rev, float* __restrict__ env,
    float* __restrict__ amp, float* __restrict__ fenv)
{
    int b = blockIdx.x;
    int t = threadIdx.x;  // 0..127
    const float* pk = packed + b * 464;
    __shared__ double sh_num[128];
    __shared__ double sh_den[128];
    __shared__ double amp_d[128];

    // softmax(p[0:128]) dot frequencies   (no max-subtract needed: inputs in (0,1))
    double e_t = exp(dsig((double)pk[t]));
    sh_den[t] = e_t;
    sh_num[t] = e_t * (double)freqs[t];

    // amp = sigmoid(p[256:384])*2-1
    double av = dsig((double)pk[256 + t]) * 2.0 - 1.0;
    amp_d[t] = av;
    amp[b * 128 + t] = (float)av;

    // noise filter env = sigmoid(p[400:464])
    if (t < 64) fenv[b * 64 + t] = (float)dsig((double)pk[400 + t]);
    __syncthreads();

    for (int off = 64; off > 0; off >>= 1) {
        if (t < off) { sh_den[t] += sh_den[t + off]; sh_num[t] += sh_num[t + off]; }
        __syncthreads();
    }

    if (t < 8) {
        const double NYQ = 11025.0;
        const double MIN_F0 = 40.0 / NYQ;
        const double MAX_F0 = 3000.0 / NYQ;
        const double F0_SPAN = MAX_F0 - MIN_F0;
        double f0 = sh_num[0] / sh_den[0];
        double F = f0 * NYQ;
        double G = MIN_F0 + F * F0_SPAN;
        double oscf = G * (double)(t + 1);
        double r = oscf / NYQ * M_PI;          // per-sample phase increment (radians)
        rev[b * 8 + t] = r / (2.0 * M_PI);     // revolutions

        // sequential amp scan for this harmonic
        double ha = dsig((double)pk[384 + t]);
        double hd = 0.9 + dsig((double)pk[392 + t]) * (1.0 - 0.9);
        double cur = 0.0;
        float* eo = env + (size_t)(b * 8 + t) * 128;
        for (int fr = 0; fr < 128; fr++) {
            cur = cur + amp_d[fr] * ha;
            cur = fmin(fmax(cur, 0.0), 1.0);
            eo[fr] = (float)cur;
            cur *= hd;
        }
    }
}

// ---------------------------------------------------------------------------
// Kernel 2: per-batch filtered noise via real-FFT-as-half-size-complex-FFT.
// Forward radix-2 DIF (natural->bitrev), combine+filter in bitrev indexing,
// inverse radix-2 DIT with conjugate twiddles (bitrev->natural). 1/M folded
// into the combine. Output multiplied by clip(lin_interp(amp),0,1).
// ---------------------------------------------------------------------------
__device__ __forceinline__ float hinterp64(const float* f, int j) {
    // lin_interp of 64 values to 16384 (j in 0..16383); H[16384] handled as 0 by caller
    float pos = ((float)j + 0.5f) * (1.0f / 256.0f) - 0.5f;
    pos = fminf(fmaxf(pos, 0.0f), 63.0f);
    int lo = (int)pos;
    int hi = min(lo + 1, 63);
    float w = pos - (float)lo;
    return f[lo] * (1.0f - w) + f[hi] * w;
}

__global__ __launch_bounds__(1024) void fft_kernel(
    const float* __restrict__ noise, const float* __restrict__ amp,
    const float* __restrict__ fenv, float* __restrict__ filt)
{
    __shared__ float2 z[MHALF];      // 128 KiB
    __shared__ float fenv_s[64];
    __shared__ float amp_s[128];
    int b = blockIdx.x;
    int tid = threadIdx.x;

    const float2* nz = (const float2*)(noise + (size_t)b * NSAMP);
    for (int m = tid; m < MHALF; m += 1024) {
        float2 v = nz[m];
        z[m] = make_float2(v.x * 2.0f - 1.0f, v.y * 2.0f - 1.0f);  // noise*2-1 packed even/odd
    }
    if (tid < 64) fenv_s[tid] = fenv[b * 64 + tid];
    if (tid < 128) amp_s[tid] = amp[b * 128 + tid];
    __syncthreads();

    // ---- forward DIF ----
    for (int h = 8192; h >= 1; h >>= 1) {
        for (int j = tid; j < 8192; j += 1024) {
            int pos = j & (h - 1);
            int i1 = ((j & ~(h - 1)) << 1) | pos;
            int i2 = i1 + h;
            float2 a = z[i1], c = z[i2];
            float dx = a.x - c.x, dy = a.y - c.y;
            float ang = -(float)M_PI * (float)pos / (float)h;
            float sn, cs;
            __sincosf(ang, &sn, &cs);
            z[i1] = make_float2(a.x + c.x, a.y + c.y);
            z[i2] = make_float2(dx * cs - dy * sn, dx * sn + dy * cs);
        }
        __syncthreads();
    }

    // ---- spectral combine: unpack rfft bins, multiply by H, repack for inverse ----
    const float invM = 1.0f / (float)MHALF;
    for (int k = tid; k <= 8192; k += 1024) {
        if (k == 0) {
            // X[0]=Re+Im, X[M]=Re-Im, Y[M]=0 (H pad). Z'[0] = (Y0/2, Y0/2)
            float2 Z0 = z[0];
            float Y0 = (Z0.x + Z0.y) * hinterp64(fenv_s, 0);
            float v = Y0 * 0.5f * invM;
            z[0] = make_float2(v, v);
        } else if (k == 8192) {
            // Z'[M/2] = Z[M/2] * H[M/2];  bitrev(M/2)=1
            float s = hinterp64(fenv_s, 8192) * invM;
            float2 Zk = z[1];
            z[1] = make_float2(Zk.x * s, Zk.y * s);
        } else {
            int ik  = (int)(__brev((unsigned)k) >> 18);
            int imk = (int)(__brev((unsigned)(16384 - k)) >> 18);
            float2 Zk = z[ik], Zm = z[imk];
            float Ex = 0.5f * (Zk.x + Zm.x);
            float Ey = 0.5f * (Zk.y - Zm.y);
            float Ox = 0.5f * (Zk.y + Zm.y);
            float Oy = -0.5f * (Zk.x - Zm.x);
            float ang = (float)M_PI * (float)k * (1.0f / 16384.0f);  // tw = e^{-i*ang} = (cs,-sn)
            float sn, cs;
            __sincosf(ang, &sn, &cs);
            float Xkx = Ex + cs * Ox + sn * Oy;
            float Xky = Ey + cs * Oy - sn * Ox;
            float Xmx = Ex - cs * Ox - sn * Oy;
            float Xmy = -Ey + cs * Oy - sn * Ox;
            float Hk = hinterp64(fenv_s, k);
            float Hm = hinterp64(fenv_s, 16384 - k);
            float Ykx = Xkx * Hk, Yky = Xky * Hk;
            float Ymx = Xmx * Hm, Ymy = Xmy * Hm;
            float Er = 0.5f * (Ykx + Ymx);
            float Ei = 0.5f * (Yky - Ymy);
            float Pr = 0.5f * (Ykx - Ymx);
            float Pi = 0.5f * (Yky + Ymy);
            float Oyx = Pr * cs - Pi * sn;   // O_y = P * conj(tw) = P*(cs,sn)
            float Oyy = Pr * sn + Pi * cs;
            z[ik]  = make_float2((Er - Oyy) * invM, (Ei + Oyx) * invM);
            z[imk] = make_float2((Er + Oyy) * invM, (-Ei + Oyx) * invM);
        }
    }
    __syncthreads();

    // ---- inverse DIT (conjugate twiddles), bitrev input -> natural output ----
    for (int h = 1; h <= 8192; h <<= 1) {
        for (int j = tid; j < 8192; j += 1024) {
            int pos = j & (h - 1);
            int i1 = ((j & ~(h - 1)) << 1) | pos;
            int i2 = i1 + h;
            float ang = (float)M_PI * (float)pos / (float)h;
            float sn, cs;
            __sincosf(ang, &sn, &cs);
            float2 a = z[i1], c = z[i2];
            float br = c.x * cs - c.y * sn;
            float bi = c.x * sn + c.y * cs;
            z[i1] = make_float2(a.x + br, a.y + bi);
            z[i2] = make_float2(a.x - br, a.y - bi);
        }
        __syncthreads();
    }

    // ---- apply clip(lin_interp(amp),0,1) and store filt ----
    float2* fo = (float2*)(filt + (size_t)b * NSAMP);
    for (int m = tid; m < MHALF; m += 1024) {
        float2 y = z[m];
        int s0 = 2 * m;
        float p0 = ((float)s0 + 0.5f) * (1.0f / 256.0f) - 0.5f;
        float p1 = p0 + (1.0f / 256.0f);
        p0 = fminf(fmaxf(p0, 0.0f), 127.0f);
        p1 = fminf(fmaxf(p1, 0.0f), 127.0f);
        int l0 = (int)p0, l1 = (int)p1;
        int h0 = min(l0 + 1, 127), h1 = min(l1 + 1, 127);
        float w0 = p0 - (float)l0, w1 = p1 - (float)l1;
        float a0 = amp_s[l0] * (1.0f - w0) + amp_s[h0] * w0;
        float a1 = amp_s[l1] * (1.0f - w1) + amp_s[h1] * w1;
        a0 = fminf(fmaxf(a0, 0.0f), 1.0f);
        a1 = fminf(fmaxf(a1, 0.0f), 1.0f);
        fo[m] = make_float2(y.x * a0, y.y * a1);
    }
}

// ---------------------------------------------------------------------------
// Kernel 3: final synthesis. out[g,s] = sum_e ( 8*filt[b,s]
//            + sum_h lerp(env[b,h],s) * sin(2*pi*frac(rev[b,h]*(s+1))) )
// ---------------------------------------------------------------------------
__global__ __launch_bounds__(256) void synth_kernel(
    const double* __restrict__ rev, const float* __restrict__ env,
    const float* __restrict__ filt, float* __restrict__ out)
{
    int chunk = blockIdx.x;  // 0..31 (1024-sample chunks)
    int g = blockIdx.y;      // 0..31 (output groups)
    int tid = threadIdx.x;
    __shared__ float env_s[64][128];   // [e*8+h][frame]
    __shared__ double rev_s[64];

    const float* eg = env + (size_t)g * 64 * 128;
    for (int i = tid; i < 64 * 128; i += 256) env_s[i >> 7][i & 127] = eg[i];
    if (tid < 64) rev_s[tid] = rev[g * 64 + tid];
    __syncthreads();

    int base = chunk * 1024;
    for (int ii = 0; ii < 4; ii++) {
        int s = base + ii * 256 + tid;
        float pos = ((float)s + 0.5f) * (1.0f / 256.0f) - 0.5f;
        pos = fminf(fmaxf(pos, 0.0f), 127.0f);
        int lo = (int)pos;
        int hi = min(lo + 1, 127);
        float w = pos - (float)lo;
        double sd = (double)(s + 1);
        float acc = 0.0f, accF = 0.0f;
        for (int e = 0; e < 8; e++) {
            accF += filt[((size_t)(g * 8 + e)) * NSAMP + s];
#pragma unroll
            for (int h = 0; h < 8; h++) {
                int idx = e * 8 + h;
                float ev = env_s[idx][lo] * (1.0f - w) + env_s[idx][hi] * w;
                double rv = rev_s[idx] * sd;
                double fr = rv - floor(rv);
                float osc = __sinf(6.283185307179586f * (float)fr);
                acc += ev * osc;
            }
        }
        out[(size_t)g * NSAMP + s] = acc + 8.0f * accF;
    }
}

// ---------------------------------------------------------------------------
// ws layout (bytes):
//   [0, 16384)                     rev    : 256*8 double
//   [16384, 16384+1MiB)            env    : 256*8*128 f32
//   [+1MiB, +1MiB+128KiB)          amp    : 256*128 f32
//   [+128KiB, +64KiB)              fenv   : 256*64 f32
//   [1261568, +32MiB)              filt   : 256*32768 f32
// total ~33.2 MB
// ---------------------------------------------------------------------------
extern "C" void kernel_launch(void* const* d_in, const int* in_sizes, int n_in,
                              void* d_out, int out_size, void* d_ws, size_t ws_size,
                              hipStream_t stream)
{
    (void)in_sizes; (void)n_in; (void)out_size; (void)ws_size;
    const float* packed = (const float*)d_in[0];
    const float* freqs  = (const float*)d_in[1];
    const float* noise  = (const float*)d_in[2];
    float* out = (float*)d_out;
    char* ws = (char*)d_ws;

    double* rev = (double*)(ws);
    float* env  = (float*)(ws + 16384);
    float* amp  = (float*)(ws + 16384 + 1048576);
    float* fenv = (float*)(ws + 16384 + 1048576 + 131072);
    float* filt = (float*)(ws + 16384 + 1048576 + 131072 + 65536);

    hipLaunchKernelGGL(prep_kernel, dim3(256), dim3(128), 0, stream,
                       packed, freqs, rev, env, amp, fenv);
    hipLaunchKernelGGL(fft_kernel, dim3(256), dim3(1024), 0, stream,
                       noise, amp, fenv, filt);
    hipLaunchKernelGGL(synth_kernel, dim3(32, 32), dim3(256), 0, stream,
                       rev, env, filt, out);
}

// Round 2
// 159.695 us; speedup vs baseline: 1.3456x; 1.3456x over previous
//
#include <hip/hip_runtime.h>
#include <math.h>

#ifndef M_PI
#define M_PI 3.14159265358979323846
#endif

#define NSAMP 32768
#define MHALF 16384
#define TWO_PI_F 6.2831853071795864f

__device__ __forceinline__ double dsig(double x) { return 1.0 / (1.0 + exp(-x)); }

// ---------------------------------------------------------------------------
// Kernel 1: per-batch parameter decode (fp64 to match the np/f64 reference)
// ---------------------------------------------------------------------------
__global__ __launch_bounds__(128) void prep_kernel(
    const float* __restrict__ packed, const float* __restrict__ freqs,
    double* __restrict__ rev, float* __restrict__ env,
    float* __restrict__ amp, float* __restrict__ fenv)
{
    int b = blockIdx.x;
    int t = threadIdx.x;  // 0..127
    const float* pk = packed + b * 464;
    __shared__ double sh_num[128];
    __shared__ double sh_den[128];
    __shared__ double amp_d[128];

    double e_t = exp(dsig((double)pk[t]));
    sh_den[t] = e_t;
    sh_num[t] = e_t * (double)freqs[t];

    double av = dsig((double)pk[256 + t]) * 2.0 - 1.0;
    amp_d[t] = av;
    amp[b * 128 + t] = (float)av;

    if (t < 64) fenv[b * 64 + t] = (float)dsig((double)pk[400 + t]);
    __syncthreads();

    for (int off = 64; off > 0; off >>= 1) {
        if (t < off) { sh_den[t] += sh_den[t + off]; sh_num[t] += sh_num[t + off]; }
        __syncthreads();
    }

    if (t < 8) {
        const double NYQ = 11025.0;
        const double MIN_F0 = 40.0 / NYQ;
        const double MAX_F0 = 3000.0 / NYQ;
        const double F0_SPAN = MAX_F0 - MIN_F0;
        double f0 = sh_num[0] / sh_den[0];
        double F = f0 * NYQ;
        double G = MIN_F0 + F * F0_SPAN;
        double oscf = G * (double)(t + 1);
        double r = oscf / NYQ * M_PI;
        rev[b * 8 + t] = r / (2.0 * M_PI);

        double ha = dsig((double)pk[384 + t]);
        double hd = 0.9 + dsig((double)pk[392 + t]) * (1.0 - 0.9);
        double cur = 0.0;
        float* eo = env + (size_t)(b * 8 + t) * 128;
        for (int fr = 0; fr < 128; fr++) {
            cur = cur + amp_d[fr] * ha;
            cur = fmin(fmax(cur, 0.0), 1.0);
            eo[fr] = (float)cur;
            cur *= hd;
        }
    }
}

// ---------------------------------------------------------------------------
// Kernel 2: register-resident 4-pass FFT (16384 = 4 x 16 x 16 x 16)
// ---------------------------------------------------------------------------
__device__ __forceinline__ float2 cmulc(float2 a, float2 b) {
    return make_float2(a.x * b.x - a.y * b.y, a.x * b.y + a.y * b.x);
}
__device__ __forceinline__ float2 twid(float2 a, float ang) {
    float sn, cs; __sincosf(ang, &sn, &cs);
    return make_float2(a.x * cs - a.y * sn, a.x * sn + a.y * cs);
}

template<int INV>
__device__ __forceinline__ void fft4(float2& x0, float2& x1, float2& x2, float2& x3) {
    float2 s02 = make_float2(x0.x + x2.x, x0.y + x2.y);
    float2 d02 = make_float2(x0.x - x2.x, x0.y - x2.y);
    float2 s13 = make_float2(x1.x + x3.x, x1.y + x3.y);
    float2 d13 = make_float2(x1.x - x3.x, x1.y - x3.y);
    float2 j13 = INV ? make_float2(-d13.y, d13.x) : make_float2(d13.y, -d13.x);
    x0 = make_float2(s02.x + s13.x, s02.y + s13.y);
    x2 = make_float2(s02.x - s13.x, s02.y - s13.y);
    x1 = make_float2(d02.x + j13.x, d02.y + j13.y);
    x3 = make_float2(d02.x - j13.x, d02.y - j13.y);
}

// After fft16, natural-order output index c lives in register V16(v,c).
#define V16(v, c) v[((((c) & 3) << 2) | ((c) >> 2))]

template<int INV>
__device__ __forceinline__ void fft16(float2 v[16]) {
    const float s = INV ? 1.0f : -1.0f;
#pragma unroll
    for (int b = 0; b < 4; b++) fft4<INV>(v[b], v[4 + b], v[8 + b], v[12 + b]);
    // G[beta][p] at v[4p+beta] *= W16^(beta*p), W16^j = (cos(2pi j/16), s*sin(2pi j/16))
    v[5]  = cmulc(v[5],  make_float2(0.9238795325f,  s * 0.3826834324f));   // j=1
    v[9]  = cmulc(v[9],  make_float2(0.7071067812f,  s * 0.7071067812f));   // j=2
    v[13] = cmulc(v[13], make_float2(0.3826834324f,  s * 0.9238795325f));   // j=3
    v[6]  = cmulc(v[6],  make_float2(0.7071067812f,  s * 0.7071067812f));   // j=2
    v[10] = cmulc(v[10], make_float2(0.0f,           s * 1.0f));            // j=4
    v[14] = cmulc(v[14], make_float2(-0.7071067812f, s * 0.7071067812f));   // j=6
    v[7]  = cmulc(v[7],  make_float2(0.3826834324f,  s * 0.9238795325f));   // j=3
    v[11] = cmulc(v[11], make_float2(-0.7071067812f, s * 0.7071067812f));   // j=6
    v[15] = cmulc(v[15], make_float2(-0.9238795325f, s * -0.3826834324f));  // j=9
#pragma unroll
    for (int p = 0; p < 4; p++) fft4<INV>(v[4 * p], v[4 * p + 1], v[4 * p + 2], v[4 * p + 3]);
}

__device__ __forceinline__ int physA(int A) { return A + (A >> 6); }

__device__ __forceinline__ float hinterp64(const float* f, int j) {
    float pos = ((float)j + 0.5f) * (1.0f / 256.0f) - 0.5f;
    pos = fminf(fmaxf(pos, 0.0f), 63.0f);
    int lo = (int)pos;
    int hi = min(lo + 1, 63);
    float w = pos - (float)lo;
    return f[lo] * (1.0f - w) + f[hi] * w;
}

// passes 2..4 shared by forward/inverse. Entry: z holds L1[c0*4096 + b],
// preceded by a barrier. Exit: z holds natural-order (swizzled) result, after barrier.
template<int INV>
__device__ __forceinline__ void passes234(float2* z, int tid) {
    const float sgn = INV ? 1.0f : -1.0f;
    const int c0 = tid >> 8;
    // ---- pass 2: 16-pt FFT over a' (stride 256) ----
    {
        const int bp = tid & 255;
        float2 v[16];
        const int base = c0 * 4096 + bp;
#pragma unroll
        for (int a = 0; a < 16; a++) v[a] = z[base + 256 * a];
        __syncthreads();
        fft16<INV>(v);
        const float w0 = sgn * (TWO_PI_F / 4096.f) * (float)bp;
        z[(c0 * 16 + 0) * 257 + bp] = V16(v, 0);
#pragma unroll
        for (int c1 = 1; c1 < 16; c1++)
            z[(c0 * 16 + c1) * 257 + bp] = twid(V16(v, c1), w0 * (float)c1);
        __syncthreads();
    }
    // ---- pass 3: 16-pt FFT over a'' (stride 16) ----
    {
        const int c1 = (tid >> 4) & 15, b2 = tid & 15;
        float2 v[16];
        const int base = (c0 * 16 + c1) * 257 + b2;
#pragma unroll
        for (int a = 0; a < 16; a++) v[a] = z[base + 16 * a];
        __syncthreads();
        fft16<INV>(v);
        const float w0 = sgn * (TWO_PI_F / 256.f) * (float)b2;
        z[((c0 * 16 + c1) * 16 + 0) * 17 + b2] = V16(v, 0);
#pragma unroll
        for (int c2 = 1; c2 < 16; c2++)
            z[((c0 * 16 + c1) * 16 + c2) * 17 + b2] = twid(V16(v, c2), w0 * (float)c2);
        __syncthreads();
    }
    // ---- pass 4: 16-pt FFT over b'' (stride 1), write natural-order swizzled ----
    {
        const int c1 = (tid >> 4) & 15, c2 = tid & 15;
        float2 v[16];
        const int base = ((c0 * 16 + c1) * 16 + c2) * 17;
#pragma unroll
        for (int b = 0; b < 16; b++) v[b] = z[base + b];
        __syncthreads();
        fft16<INV>(v);
        const int A0 = 64 * c2 + 4 * c1 + c0;
#pragma unroll
        for (int c3 = 0; c3 < 16; c3++) {
            int A = 1024 * c3 + A0;
            z[physA(A)] = V16(v, c3);
        }
        __syncthreads();
    }
}

__global__ __launch_bounds__(1024) void fft_kernel(
    const float* __restrict__ noise, const float* __restrict__ amp,
    const float* __restrict__ fenv, float* __restrict__ filt)
{
    __shared__ float2 z[17408];     // 139264 B, covers L1/L2/L3/LC layouts
    __shared__ float fenv_s[64];
    __shared__ float amp_s[128];
    const int bb = blockIdx.x;
    const int tid = threadIdx.x;

    if (tid < 64) fenv_s[tid] = fenv[bb * 64 + tid];
    if (tid < 128) amp_s[tid] = amp[bb * 128 + tid];

    const float2* nz = (const float2*)(noise + (size_t)bb * NSAMP);

    // ---- forward pass 1: 4-pt FFT over a (stride 4096) ----
    {
        float2 v[16];
#pragma unroll
        for (int m = 0; m < 4; m++)
#pragma unroll
            for (int a = 0; a < 4; a++) {
                float2 t = nz[a * 4096 + m * 1024 + tid];
                v[m * 4 + a] = make_float2(t.x * 2.f - 1.f, t.y * 2.f - 1.f);
            }
#pragma unroll
        for (int m = 0; m < 4; m++) {
            fft4<0>(v[m * 4 + 0], v[m * 4 + 1], v[m * 4 + 2], v[m * 4 + 3]);
            float w0 = -(TWO_PI_F / 16384.f) * (float)(m * 1024 + tid);
#pragma unroll
            for (int c0 = 1; c0 < 4; c0++) v[m * 4 + c0] = twid(v[m * 4 + c0], w0 * (float)c0);
#pragma unroll
            for (int c0 = 0; c0 < 4; c0++) z[c0 * 4096 + m * 1024 + tid] = v[m * 4 + c0];
        }
    }
    __syncthreads();
    passes234<0>(z, tid);

    // ---- spectral combine: unpack rfft bins, multiply by H, repack, fold 1/M ----
    const float invM = 1.0f / (float)MHALF;
    for (int k = tid; k <= 8192; k += 1024) {
        if (k == 0) {
            float2 Z0 = z[physA(0)];
            float Y0 = (Z0.x + Z0.y) * hinterp64(fenv_s, 0);
            float vv = Y0 * 0.5f * invM;
            z[physA(0)] = make_float2(vv, vv);
        } else if (k == 8192) {
            float s = hinterp64(fenv_s, 8192) * invM;
            float2 Zk = z[physA(8192)];
            z[physA(8192)] = make_float2(Zk.x * s, Zk.y * s);
        } else {
            int ik = physA(k), imk = physA(16384 - k);
            float2 Zk = z[ik], Zm = z[imk];
            float Ex = 0.5f * (Zk.x + Zm.x);
            float Ey = 0.5f * (Zk.y - Zm.y);
            float Ox = 0.5f * (Zk.y + Zm.y);
            float Oy = -0.5f * (Zk.x - Zm.x);
            float ang = (float)M_PI * (float)k * (1.0f / 16384.0f);
            float sn, cs;
            __sincosf(ang, &sn, &cs);
            float Xkx = Ex + cs * Ox + sn * Oy;
            float Xky = Ey + cs * Oy - sn * Ox;
            float Xmx = Ex - cs * Ox - sn * Oy;
            float Xmy = -Ey + cs * Oy - sn * Ox;
            float Hk = hinterp64(fenv_s, k);
            float Hm = hinterp64(fenv_s, 16384 - k);
            float Ykx = Xkx * Hk, Yky = Xky * Hk;
            float Ymx = Xmx * Hm, Ymy = Xmy * Hm;
            float Er = 0.5f * (Ykx + Ymx);
            float Ei = 0.5f * (Yky - Ymy);
            float Pr = 0.5f * (Ykx - Ymx);
            float Pi = 0.5f * (Yky + Ymy);
            float Oyx = Pr * cs - Pi * sn;
            float Oyy = Pr * sn + Pi * cs;
            z[ik]  = make_float2((Er - Oyy) * invM, (Ei + Oyx) * invM);
            z[imk] = make_float2((Er + Oyy) * invM, (-Ei + Oyx) * invM);
        }
    }
    __syncthreads();

    // ---- inverse pass 1 ----
    {
        float2 v[16];
#pragma unroll
        for (int m = 0; m < 4; m++)
#pragma unroll
            for (int a = 0; a < 4; a++) {
                int A = a * 4096 + m * 1024 + tid;
                v[m * 4 + a] = z[physA(A)];
            }
        __syncthreads();
#pragma unroll
        for (int m = 0; m < 4; m++) {
            fft4<1>(v[m * 4 + 0], v[m * 4 + 1], v[m * 4 + 2], v[m * 4 + 3]);
            float w0 = (TWO_PI_F / 16384.f) * (float)(m * 1024 + tid);
#pragma unroll
            for (int c0 = 1; c0 < 4; c0++) v[m * 4 + c0] = twid(v[m * 4 + c0], w0 * (float)c0);
#pragma unroll
            for (int c0 = 0; c0 < 4; c0++) z[c0 * 4096 + m * 1024 + tid] = v[m * 4 + c0];
        }
    }
    __syncthreads();
    passes234<1>(z, tid);

    // ---- apply clip(lin_interp(amp),0,1) and store filt ----
    float2* fo = (float2*)(filt + (size_t)bb * NSAMP);
    for (int m = tid; m < MHALF; m += 1024) {
        float2 y = z[physA(m)];
        int s0 = 2 * m;
        float p0 = ((float)s0 + 0.5f) * (1.0f / 256.0f) - 0.5f;
        float p1 = p0 + (1.0f / 256.0f);
        p0 = fminf(fmaxf(p0, 0.0f), 127.0f);
        p1 = fminf(fmaxf(p1, 0.0f), 127.0f);
        int l0 = (int)p0, l1 = (int)p1;
        int h0 = min(l0 + 1, 127), h1 = min(l1 + 1, 127);
        float w0 = p0 - (float)l0, w1 = p1 - (float)l1;
        float a0 = amp_s[l0] * (1.0f - w0) + amp_s[h0] * w0;
        float a1 = amp_s[l1] * (1.0f - w1) + amp_s[h1] * w1;
        a0 = fminf(fmaxf(a0, 0.0f), 1.0f);
        a1 = fminf(fmaxf(a1, 0.0f), 1.0f);
        fo[m] = make_float2(y.x * a0, y.y * a1);
    }
}

// ---------------------------------------------------------------------------
// Kernel 3: final synthesis (unchanged)
// ---------------------------------------------------------------------------
__global__ __launch_bounds__(256) void synth_kernel(
    const double* __restrict__ rev, const float* __restrict__ env,
    const float* __restrict__ filt, float* __restrict__ out)
{
    int chunk = blockIdx.x;
    int g = blockIdx.y;
    int tid = threadIdx.x;
    __shared__ float env_s[64][128];
    __shared__ double rev_s[64];

    const float* eg = env + (size_t)g * 64 * 128;
    for (int i = tid; i < 64 * 128; i += 256) env_s[i >> 7][i & 127] = eg[i];
    if (tid < 64) rev_s[tid] = rev[g * 64 + tid];
    __syncthreads();

    int base = chunk * 1024;
    for (int ii = 0; ii < 4; ii++) {
        int s = base + ii * 256 + tid;
        float pos = ((float)s + 0.5f) * (1.0f / 256.0f) - 0.5f;
        pos = fminf(fmaxf(pos, 0.0f), 127.0f);
        int lo = (int)pos;
        int hi = min(lo + 1, 127);
        float w = pos - (float)lo;
        double sd = (double)(s + 1);
        float acc = 0.0f, accF = 0.0f;
        for (int e = 0; e < 8; e++) {
            accF += filt[((size_t)(g * 8 + e)) * NSAMP + s];
#pragma unroll
            for (int h = 0; h < 8; h++) {
                int idx = e * 8 + h;
                float ev = env_s[idx][lo] * (1.0f - w) + env_s[idx][hi] * w;
                double rv = rev_s[idx] * sd;
                double fr = rv - floor(rv);
                float osc = __sinf(6.283185307179586f * (float)fr);
                acc += ev * osc;
            }
        }
        out[(size_t)g * NSAMP + s] = acc + 8.0f * accF;
    }
}

extern "C" void kernel_launch(void* const* d_in, const int* in_sizes, int n_in,
                              void* d_out, int out_size, void* d_ws, size_t ws_size,
                              hipStream_t stream)
{
    (void)in_sizes; (void)n_in; (void)out_size; (void)ws_size;
    const float* packed = (const float*)d_in[0];
    const float* freqs  = (const float*)d_in[1];
    const float* noise  = (const float*)d_in[2];
    float* out = (float*)d_out;
    char* ws = (char*)d_ws;

    double* rev = (double*)(ws);
    float* env  = (float*)(ws + 16384);
    float* amp  = (float*)(ws + 16384 + 1048576);
    float* fenv = (float*)(ws + 16384 + 1048576 + 131072);
    float* filt = (float*)(ws + 16384 + 1048576 + 131072 + 65536);

    hipLaunchKernelGGL(prep_kernel, dim3(256), dim3(128), 0, stream,
                       packed, freqs, rev, env, amp, fenv);
    hipLaunchKernelGGL(fft_kernel, dim3(256), dim3(1024), 0, stream,
                       noise, amp, fenv, filt);
    hipLaunchKernelGGL(synth_kernel, dim3(32, 32), dim3(256), 0, stream,
                       rev, env, filt, out);
}

// Round 3
// 138.608 us; speedup vs baseline: 1.5503x; 1.1521x over previous
//
#include <hip/hip_runtime.h>
#include <math.h>

#ifndef M_PI
#define M_PI 3.14159265358979323846
#endif

#define NSAMP 32768
#define MHALF 16384
#define TWO_PI_F 6.2831853071795864f

__device__ __forceinline__ double dsig(double x) { return 1.0 / (1.0 + exp(-x)); }

// ---------------------------------------------------------------------------
// Kernel 1: per-batch parameter decode (fp64 to match the np/f64 reference).
// Emits per-oscillator phase step as Q0.64 fixed point (u64).
// ---------------------------------------------------------------------------
__global__ __launch_bounds__(128) void prep_kernel(
    const float* __restrict__ packed, const float* __restrict__ freqs,
    unsigned long long* __restrict__ step, float* __restrict__ env,
    float* __restrict__ amp, float* __restrict__ fenv)
{
    int b = blockIdx.x;
    int t = threadIdx.x;  // 0..127
    const float* pk = packed + b * 464;
    __shared__ double sh_num[128];
    __shared__ double sh_den[128];
    __shared__ double amp_d[128];

    double e_t = exp(dsig((double)pk[t]));
    sh_den[t] = e_t;
    sh_num[t] = e_t * (double)freqs[t];

    double av = dsig((double)pk[256 + t]) * 2.0 - 1.0;
    amp_d[t] = av;
    amp[b * 128 + t] = (float)av;

    if (t < 64) fenv[b * 64 + t] = (float)dsig((double)pk[400 + t]);
    __syncthreads();

    for (int off = 64; off > 0; off >>= 1) {
        if (t < off) { sh_den[t] += sh_den[t + off]; sh_num[t] += sh_num[t + off]; }
        __syncthreads();
    }

    if (t < 8) {
        const double NYQ = 11025.0;
        const double MIN_F0 = 40.0 / NYQ;
        const double MAX_F0 = 3000.0 / NYQ;
        const double F0_SPAN = MAX_F0 - MIN_F0;
        double f0 = sh_num[0] / sh_den[0];
        double F = f0 * NYQ;
        double G = MIN_F0 + F * F0_SPAN;
        double oscf = G * (double)(t + 1);
        double r = oscf / NYQ * M_PI;          // radians / sample
        double rv = r / (2.0 * M_PI);          // revolutions / sample
        rv -= floor(rv);                       // integer revs don't matter
        step[b * 8 + t] = (unsigned long long)(rv * 18446744073709551616.0);

        double ha = dsig((double)pk[384 + t]);
        double hd = 0.9 + dsig((double)pk[392 + t]) * (1.0 - 0.9);
        double cur = 0.0;
        float* eo = env + (size_t)(b * 8 + t) * 128;
        for (int fr = 0; fr < 128; fr++) {
            cur = cur + amp_d[fr] * ha;
            cur = fmin(fmax(cur, 0.0), 1.0);
            eo[fr] = (float)cur;
            cur *= hd;
        }
    }
}

// ---------------------------------------------------------------------------
// Kernel 2: register-resident 4-pass FFT (16384 = 4 x 16 x 16 x 16)
// ---------------------------------------------------------------------------
__device__ __forceinline__ float2 cmulc(float2 a, float2 b) {
    return make_float2(a.x * b.x - a.y * b.y, a.x * b.y + a.y * b.x);
}
__device__ __forceinline__ float2 twid(float2 a, float ang) {
    float sn, cs; __sincosf(ang, &sn, &cs);
    return make_float2(a.x * cs - a.y * sn, a.x * sn + a.y * cs);
}

template<int INV>
__device__ __forceinline__ void fft4(float2& x0, float2& x1, float2& x2, float2& x3) {
    float2 s02 = make_float2(x0.x + x2.x, x0.y + x2.y);
    float2 d02 = make_float2(x0.x - x2.x, x0.y - x2.y);
    float2 s13 = make_float2(x1.x + x3.x, x1.y + x3.y);
    float2 d13 = make_float2(x1.x - x3.x, x1.y - x3.y);
    float2 j13 = INV ? make_float2(-d13.y, d13.x) : make_float2(d13.y, -d13.x);
    x0 = make_float2(s02.x + s13.x, s02.y + s13.y);
    x2 = make_float2(s02.x - s13.x, s02.y - s13.y);
    x1 = make_float2(d02.x + j13.x, d02.y + j13.y);
    x3 = make_float2(d02.x - j13.x, d02.y - j13.y);
}

#define V16(v, c) v[((((c) & 3) << 2) | ((c) >> 2))]

template<int INV>
__device__ __forceinline__ void fft16(float2 v[16]) {
    const float s = INV ? 1.0f : -1.0f;
#pragma unroll
    for (int b = 0; b < 4; b++) fft4<INV>(v[b], v[4 + b], v[8 + b], v[12 + b]);
    v[5]  = cmulc(v[5],  make_float2(0.9238795325f,  s * 0.3826834324f));
    v[9]  = cmulc(v[9],  make_float2(0.7071067812f,  s * 0.7071067812f));
    v[13] = cmulc(v[13], make_float2(0.3826834324f,  s * 0.9238795325f));
    v[6]  = cmulc(v[6],  make_float2(0.7071067812f,  s * 0.7071067812f));
    v[10] = cmulc(v[10], make_float2(0.0f,           s * 1.0f));
    v[14] = cmulc(v[14], make_float2(-0.7071067812f, s * 0.7071067812f));
    v[7]  = cmulc(v[7],  make_float2(0.3826834324f,  s * 0.9238795325f));
    v[11] = cmulc(v[11], make_float2(-0.7071067812f, s * 0.7071067812f));
    v[15] = cmulc(v[15], make_float2(-0.9238795325f, s * -0.3826834324f));
#pragma unroll
    for (int p = 0; p < 4; p++) fft4<INV>(v[4 * p], v[4 * p + 1], v[4 * p + 2], v[4 * p + 3]);
}

__device__ __forceinline__ int physA(int A) { return A + (A >> 6); }

__device__ __forceinline__ float hinterp64(const float* f, int j) {
    float pos = ((float)j + 0.5f) * (1.0f / 256.0f) - 0.5f;
    pos = fminf(fmaxf(pos, 0.0f), 63.0f);
    int lo = (int)pos;
    int hi = min(lo + 1, 63);
    float w = pos - (float)lo;
    return f[lo] * (1.0f - w) + f[hi] * w;
}

template<int INV>
__device__ __forceinline__ void passes234(float2* z, int tid) {
    const float sgn = INV ? 1.0f : -1.0f;
    const int c0 = tid >> 8;
    {
        const int bp = tid & 255;
        float2 v[16];
        const int base = c0 * 4096 + bp;
#pragma unroll
        for (int a = 0; a < 16; a++) v[a] = z[base + 256 * a];
        __syncthreads();
        fft16<INV>(v);
        const float w0 = sgn * (TWO_PI_F / 4096.f) * (float)bp;
        z[(c0 * 16 + 0) * 257 + bp] = V16(v, 0);
#pragma unroll
        for (int c1 = 1; c1 < 16; c1++)
            z[(c0 * 16 + c1) * 257 + bp] = twid(V16(v, c1), w0 * (float)c1);
        __syncthreads();
    }
    {
        const int c1 = (tid >> 4) & 15, b2 = tid & 15;
        float2 v[16];
        const int base = (c0 * 16 + c1) * 257 + b2;
#pragma unroll
        for (int a = 0; a < 16; a++) v[a] = z[base + 16 * a];
        __syncthreads();
        fft16<INV>(v);
        const float w0 = sgn * (TWO_PI_F / 256.f) * (float)b2;
        z[((c0 * 16 + c1) * 16 + 0) * 17 + b2] = V16(v, 0);
#pragma unroll
        for (int c2 = 1; c2 < 16; c2++)
            z[((c0 * 16 + c1) * 16 + c2) * 17 + b2] = twid(V16(v, c2), w0 * (float)c2);
        __syncthreads();
    }
    {
        const int c1 = (tid >> 4) & 15, c2 = tid & 15;
        float2 v[16];
        const int base = ((c0 * 16 + c1) * 16 + c2) * 17;
#pragma unroll
        for (int b = 0; b < 16; b++) v[b] = z[base + b];
        __syncthreads();
        fft16<INV>(v);
        const int A0 = 64 * c2 + 4 * c1 + c0;
#pragma unroll
        for (int c3 = 0; c3 < 16; c3++) {
            int A = 1024 * c3 + A0;
            z[physA(A)] = V16(v, c3);
        }
        __syncthreads();
    }
}

__global__ __launch_bounds__(1024) void fft_kernel(
    const float* __restrict__ noise, const float* __restrict__ amp,
    const float* __restrict__ fenv, float* __restrict__ filt)
{
    __shared__ float2 z[17408];
    __shared__ float fenv_s[64];
    __shared__ float amp_s[128];
    const int bb = blockIdx.x;
    const int tid = threadIdx.x;

    if (tid < 64) fenv_s[tid] = fenv[bb * 64 + tid];
    if (tid < 128) amp_s[tid] = amp[bb * 128 + tid];

    const float2* nz = (const float2*)(noise + (size_t)bb * NSAMP);

    {
        float2 v[16];
#pragma unroll
        for (int m = 0; m < 4; m++)
#pragma unroll
            for (int a = 0; a < 4; a++) {
                float2 t = nz[a * 4096 + m * 1024 + tid];
                v[m * 4 + a] = make_float2(t.x * 2.f - 1.f, t.y * 2.f - 1.f);
            }
#pragma unroll
        for (int m = 0; m < 4; m++) {
            fft4<0>(v[m * 4 + 0], v[m * 4 + 1], v[m * 4 + 2], v[m * 4 + 3]);
            float w0 = -(TWO_PI_F / 16384.f) * (float)(m * 1024 + tid);
#pragma unroll
            for (int c0 = 1; c0 < 4; c0++) v[m * 4 + c0] = twid(v[m * 4 + c0], w0 * (float)c0);
#pragma unroll
            for (int c0 = 0; c0 < 4; c0++) z[c0 * 4096 + m * 1024 + tid] = v[m * 4 + c0];
        }
    }
    __syncthreads();
    passes234<0>(z, tid);

    const float invM = 1.0f / (float)MHALF;
    for (int k = tid; k <= 8192; k += 1024) {
        if (k == 0) {
            float2 Z0 = z[physA(0)];
            float Y0 = (Z0.x + Z0.y) * hinterp64(fenv_s, 0);
            float vv = Y0 * 0.5f * invM;
            z[physA(0)] = make_float2(vv, vv);
        } else if (k == 8192) {
            float s = hinterp64(fenv_s, 8192) * invM;
            float2 Zk = z[physA(8192)];
            z[physA(8192)] = make_float2(Zk.x * s, Zk.y * s);
        } else {
            int ik = physA(k), imk = physA(16384 - k);
            float2 Zk = z[ik], Zm = z[imk];
            float Ex = 0.5f * (Zk.x + Zm.x);
            float Ey = 0.5f * (Zk.y - Zm.y);
            float Ox = 0.5f * (Zk.y + Zm.y);
            float Oy = -0.5f * (Zk.x - Zm.x);
            float ang = (float)M_PI * (float)k * (1.0f / 16384.0f);
            float sn, cs;
            __sincosf(ang, &sn, &cs);
            float Xkx = Ex + cs * Ox + sn * Oy;
            float Xky = Ey + cs * Oy - sn * Ox;
            float Xmx = Ex - cs * Ox - sn * Oy;
            float Xmy = -Ey + cs * Oy - sn * Ox;
            float Hk = hinterp64(fenv_s, k);
            float Hm = hinterp64(fenv_s, 16384 - k);
            float Ykx = Xkx * Hk, Yky = Xky * Hk;
            float Ymx = Xmx * Hm, Ymy = Xmy * Hm;
            float Er = 0.5f * (Ykx + Ymx);
            float Ei = 0.5f * (Yky - Ymy);
            float Pr = 0.5f * (Ykx - Ymx);
            float Pi = 0.5f * (Yky + Ymy);
            float Oyx = Pr * cs - Pi * sn;
            float Oyy = Pr * sn + Pi * cs;
            z[ik]  = make_float2((Er - Oyy) * invM, (Ei + Oyx) * invM);
            z[imk] = make_float2((Er + Oyy) * invM, (-Ei + Oyx) * invM);
        }
    }
    __syncthreads();

    {
        float2 v[16];
#pragma unroll
        for (int m = 0; m < 4; m++)
#pragma unroll
            for (int a = 0; a < 4; a++) {
                int A = a * 4096 + m * 1024 + tid;
                v[m * 4 + a] = z[physA(A)];
            }
        __syncthreads();
#pragma unroll
        for (int m = 0; m < 4; m++) {
            fft4<1>(v[m * 4 + 0], v[m * 4 + 1], v[m * 4 + 2], v[m * 4 + 3]);
            float w0 = (TWO_PI_F / 16384.f) * (float)(m * 1024 + tid);
#pragma unroll
            for (int c0 = 1; c0 < 4; c0++) v[m * 4 + c0] = twid(v[m * 4 + c0], w0 * (float)c0);
#pragma unroll
            for (int c0 = 0; c0 < 4; c0++) z[c0 * 4096 + m * 1024 + tid] = v[m * 4 + c0];
        }
    }
    __syncthreads();
    passes234<1>(z, tid);

    float2* fo = (float2*)(filt + (size_t)bb * NSAMP);
    for (int m = tid; m < MHALF; m += 1024) {
        float2 y = z[physA(m)];
        int s0 = 2 * m;
        float p0 = ((float)s0 + 0.5f) * (1.0f / 256.0f) - 0.5f;
        float p1 = p0 + (1.0f / 256.0f);
        p0 = fminf(fmaxf(p0, 0.0f), 127.0f);
        p1 = fminf(fmaxf(p1, 0.0f), 127.0f);
        int l0 = (int)p0, l1 = (int)p1;
        int h0 = min(l0 + 1, 127), h1 = min(l1 + 1, 127);
        float w0 = p0 - (float)l0, w1 = p1 - (float)l1;
        float a0 = amp_s[l0] * (1.0f - w0) + amp_s[h0] * w0;
        float a1 = amp_s[l1] * (1.0f - w1) + amp_s[h1] * w1;
        a0 = fminf(fmaxf(a0, 0.0f), 1.0f);
        a1 = fminf(fmaxf(a1, 0.0f), 1.0f);
        fo[m] = make_float2(y.x * a0, y.y * a1);
    }
}

// ---------------------------------------------------------------------------
// Kernel 3: final synthesis — integer Q0.64 phase + hw v_sin (revolutions).
// Each thread: 4 consecutive samples (float4 I/O).
// ---------------------------------------------------------------------------
__global__ __launch_bounds__(256) void synth_kernel(
    const unsigned long long* __restrict__ step, const float* __restrict__ env,
    const float* __restrict__ filt, float* __restrict__ out)
{
    const int chunk = blockIdx.x;   // 0..31
    const int g = blockIdx.y;       // 0..31
    const int tid = threadIdx.x;
    __shared__ float env_s[64 * 128];
    __shared__ unsigned long long step_s[64];

    const float* eg = env + (size_t)g * 64 * 128;
    for (int i = tid; i < 64 * 128; i += 256) env_s[i] = eg[i];
    if (tid < 64) step_s[tid] = step[g * 64 + tid];
    __syncthreads();

    const int s0 = chunk * 1024 + tid * 4;

    // filtered-noise part: 8 coalesced float4 loads
    float4 aF = make_float4(0.f, 0.f, 0.f, 0.f);
#pragma unroll
    for (int e = 0; e < 8; e++) {
        const float4 f = *(const float4*)(filt + ((size_t)(g * 8 + e)) * NSAMP + s0);
        aF.x += f.x; aF.y += f.y; aF.z += f.z; aF.w += f.w;
    }

    // env interpolation coords for the 4 samples (frame grid: 256 samples/frame)
    float c0v[4], c1v[4], c2v[4];
    int lo0;
    {
        float pos0 = ((float)s0 + 0.5f) * (1.0f / 256.0f) - 0.5f;
        pos0 = fminf(fmaxf(pos0, 0.0f), 127.0f);
        lo0 = (int)pos0;
        int lo3 = lo0;
#pragma unroll
        for (int k = 0; k < 4; k++) {
            float pos = ((float)(s0 + k) + 0.5f) * (1.0f / 256.0f) - 0.5f;
            pos = fminf(fmaxf(pos, 0.0f), 127.0f);
            int lo = (int)pos;
            float w = pos - (float)lo;
            if (lo == lo0) { c0v[k] = 1.0f - w; c1v[k] = w;        c2v[k] = 0.0f; }
            else           { c0v[k] = 0.0f;     c1v[k] = 1.0f - w; c2v[k] = w;    }
            lo3 = lo;
        }
        (void)lo3;
    }
    const int i1 = min(lo0 + 1, 127);
    // second interval's upper sample (v2); when no boundary crossed it's unused weight-0
    int lo3b = lo0;
    {
        float pos = ((float)(s0 + 3) + 0.5f) * (1.0f / 256.0f) - 0.5f;
        pos = fminf(fmaxf(pos, 0.0f), 127.0f);
        lo3b = (int)pos;
    }
    const int i2 = min(lo3b + 1, 127);

    float a0 = 0.f, a1 = 0.f, a2 = 0.f, a3 = 0.f;
    const unsigned long long n0 = (unsigned long long)(unsigned)(s0 + 1);

#pragma unroll 8
    for (int idx = 0; idx < 64; idx++) {
        const unsigned long long st = step_s[idx];
        unsigned long long p = st * n0;
        const float* er = env_s + (idx << 7);
        const float v0 = er[lo0], v1 = er[i1], v2 = er[i2];

        float ev, fr, sn;

        fr = (float)(unsigned)(p >> 32) * 0x1p-32f;
        sn = __builtin_amdgcn_sinf(fr);                 // sin(2*pi*fr)
        ev = fmaf(v0, c0v[0], fmaf(v1, c1v[0], v2 * c2v[0]));
        a0 = fmaf(ev, sn, a0); p += st;

        fr = (float)(unsigned)(p >> 32) * 0x1p-32f;
        sn = __builtin_amdgcn_sinf(fr);
        ev = fmaf(v0, c0v[1], fmaf(v1, c1v[1], v2 * c2v[1]));
        a1 = fmaf(ev, sn, a1); p += st;

        fr = (float)(unsigned)(p >> 32) * 0x1p-32f;
        sn = __builtin_amdgcn_sinf(fr);
        ev = fmaf(v0, c0v[2], fmaf(v1, c1v[2], v2 * c2v[2]));
        a2 = fmaf(ev, sn, a2); p += st;

        fr = (float)(unsigned)(p >> 32) * 0x1p-32f;
        sn = __builtin_amdgcn_sinf(fr);
        ev = fmaf(v0, c0v[3], fmaf(v1, c1v[3], v2 * c2v[3]));
        a3 = fmaf(ev, sn, a3);
    }

    float4 r;
    r.x = a0 + 8.0f * aF.x;
    r.y = a1 + 8.0f * aF.y;
    r.z = a2 + 8.0f * aF.z;
    r.w = a3 + 8.0f * aF.w;
    *(float4*)(out + (size_t)g * NSAMP + s0) = r;
}

extern "C" void kernel_launch(void* const* d_in, const int* in_sizes, int n_in,
                              void* d_out, int out_size, void* d_ws, size_t ws_size,
                              hipStream_t stream)
{
    (void)in_sizes; (void)n_in; (void)out_size; (void)ws_size;
    const float* packed = (const float*)d_in[0];
    const float* freqs  = (const float*)d_in[1];
    const float* noise  = (const float*)d_in[2];
    float* out = (float*)d_out;
    char* ws = (char*)d_ws;

    unsigned long long* step = (unsigned long long*)(ws);
    float* env  = (float*)(ws + 16384);
    float* amp  = (float*)(ws + 16384 + 1048576);
    float* fenv = (float*)(ws + 16384 + 1048576 + 131072);
    float* filt = (float*)(ws + 16384 + 1048576 + 131072 + 65536);

    hipLaunchKernelGGL(prep_kernel, dim3(256), dim3(128), 0, stream,
                       packed, freqs, step, env, amp, fenv);
    hipLaunchKernelGGL(fft_kernel, dim3(256), dim3(1024), 0, stream,
                       noise, amp, fenv, filt);
    hipLaunchKernelGGL(synth_kernel, dim3(32, 32), dim3(256), 0, stream,
                       step, env, filt, out);
}